// Round 6
// baseline (1165.142 us; speedup 1.0000x reference)
//
#include <hip/hip_runtime.h>
#include <hip/hip_bf16.h>

// Problem constants (fixed by the reference's setup_inputs)
#define NN 100000      // nodes
#define EE 50000       // hyperedges
#define CC 2000        // components
#define NNZ 1600000    // incidences
#define DD 128         // feature dim
#define ET (EE + NN)   // edges incl. self-loop edges

// Radix-partition parameters
#define PB 800         // partition blocks
#define CHUNK 2000     // items per partition block (PB*CHUNK == NNZ exactly)
#define NBK 196        // coarse buckets (= ceil(EE/256) = ceil(NN/512))
#define SCAP 12288     // LDS staging capacity (entries) for bucket_scatter

// Gather-table layouts (dim-sliced so each XCD's random gathers hit a
// 3.2 MB slice that fits the 4 MiB per-XCD L2):
//   Hb[8][NN][16]  bf16  (eighth-major: dim d of row r at [(d>>4)][r][d&15])
//   Eb[4][EE][32]  bf16  (quarter-major: dim d of row r at [(d>>5)][r][d&31])

__device__ __forceinline__ float prelu(float x, float a) {
    return x >= 0.f ? x : a * x;
}

// bf16 <-> f32 (RNE on store; exact on load)
__device__ __forceinline__ float bf2f(unsigned short h) {
    return __uint_as_float(((unsigned int)h) << 16);
}
__device__ __forceinline__ unsigned short f2bf(float f) {
    unsigned int u = __float_as_uint(f);
    u = (u + 0x7fff + ((u >> 16) & 1)) >> 16;
    return (unsigned short)u;
}

struct alignas(16) us8 { ushort4 lo, hi; };

// ---------------- tiny: component membership counts ---------------------------
__global__ void comp_hist(const int* __restrict__ hec, const int* __restrict__ ncc,
                          int* __restrict__ c1cnt, int* __restrict__ c2cnt) {
    int i = blockIdx.x * blockDim.x + threadIdx.x;
    int stride = gridDim.x * blockDim.x;
    for (int k = i; k < EE; k += stride) atomicAdd(&c1cnt[hec[k]], 1);
    for (int k = i; k < NN; k += stride) atomicAdd(&c2cnt[ncc[k]], 1);
}

// ---------------- pass A: coarse-bucket TOTALS (per-block LDS hist -> atomics) -
__global__ __launch_bounds__(256) void part_hist(const int* __restrict__ src,
                                                 const int* __restrict__ dst,
                                                 int* __restrict__ etot,
                                                 int* __restrict__ ntot) {
    __shared__ int he[NBK], hn[NBK];
    for (int i = threadIdx.x; i < NBK; i += 256) { he[i] = 0; hn[i] = 0; }
    __syncthreads();
    int b = blockIdx.x;
    int beg = b * CHUNK, end = min(beg + CHUNK, NNZ);
    for (int k = beg + threadIdx.x; k < end; k += 256) {
        atomicAdd(&he[dst[k] >> 8], 1);
        atomicAdd(&hn[src[k] >> 9], 1);
    }
    __syncthreads();
    for (int i = threadIdx.x; i < NBK; i += 256) {
        if (he[i]) atomicAdd(&etot[i], he[i]);
        if (hn[i]) atomicAdd(&ntot[i], hn[i]);
    }
}

// ---------------- pass B: tiny scan of the 196-entry bucket totals ------------
__global__ __launch_bounds__(256) void scan_small(const int* __restrict__ etot,
        const int* __restrict__ ntot, int* __restrict__ ebase, int* __restrict__ nbase,
        int* __restrict__ ecur, int* __restrict__ ncur) {
    __shared__ int se[256], sn[256];
    int t = threadIdx.x;
    int ve = (t < NBK) ? etot[t] : 0;
    int vn = (t < NBK) ? ntot[t] : 0;
    se[t] = ve; sn[t] = vn;
    __syncthreads();
    for (int off = 1; off < 256; off <<= 1) {
        int ae = (t >= off) ? se[t - off] : 0;
        int an = (t >= off) ? sn[t - off] : 0;
        __syncthreads();
        se[t] += ae; sn[t] += an;
        __syncthreads();
    }
    if (t < NBK) {
        int be = se[t] - ve, bn = sn[t] - vn;
        ebase[t] = be; ecur[t] = be;
        nbase[t] = bn; ncur[t] = bn;
    }
    if (t == 0) { ebase[NBK] = NNZ; nbase[NBK] = NNZ; }
}

// ---------------- pass C: reorder pairs into bucket-contiguous order ----------
__global__ __launch_bounds__(256) void reorder_kernel(const int* __restrict__ src,
        const int* __restrict__ dst, int* __restrict__ ecur, int* __restrict__ ncur,
        int2* __restrict__ pe, int2* __restrict__ pn) {
    __shared__ int sS[CHUNK], sD[CHUNK];
    __shared__ int he[NBK], hn[NBK];
    __shared__ int beA[NBK], bnA[NBK];
    int b = blockIdx.x;
    int beg = b * CHUNK;
    int n = min(CHUNK, NNZ - beg);
    for (int i = threadIdx.x; i < NBK; i += 256) { he[i] = 0; hn[i] = 0; }
    for (int i = threadIdx.x; i < n; i += 256) {
        sS[i] = src[beg + i];
        sD[i] = dst[beg + i];
    }
    __syncthreads();
    for (int i = threadIdx.x; i < n; i += 256) {
        atomicAdd(&he[sD[i] >> 8], 1);
        atomicAdd(&hn[sS[i] >> 9], 1);
    }
    __syncthreads();
    for (int i = threadIdx.x; i < NBK; i += 256) {
        beA[i] = he[i] ? atomicAdd(&ecur[i], he[i]) : 0;
        bnA[i] = hn[i] ? atomicAdd(&ncur[i], hn[i]) : 0;
        he[i] = 0; hn[i] = 0;   // reuse as local cursors
    }
    __syncthreads();
    for (int i = threadIdx.x; i < n; i += 256) {
        int d = sD[i], s = sS[i];
        int bk = d >> 8;
        int p = beA[bk] + atomicAdd(&he[bk], 1);
        pe[p] = make_int2(d, s);            // key=dst, payload=src
        bk = s >> 9;
        p = bnA[bk] + atomicAdd(&hn[bk], 1);
        pn[p] = make_int2(s, d);            // key=src, payload=dst
    }
}

// ---------------- pass D: per-bucket exact CSR build --------------------------
template <int W, int SHIFT>
__global__ __launch_bounds__(256) void bucket_scatter(const int2* __restrict__ pairs,
        const int* __restrict__ bases, int* __restrict__ ptr_excl,
        int* __restrict__ csr, int segn) {
    __shared__ int cnt[W];
    __shared__ int stage[SCAP];
    int b = blockIdx.x;
    int base = bases[b];
    int bend = bases[b + 1];
    int bsize = bend - base;

    for (int i = threadIdx.x; i < W; i += 256) cnt[i] = 0;
    __syncthreads();
    for (int k = base + threadIdx.x; k < bend; k += 256)
        atomicAdd(&cnt[pairs[k].x - (b << SHIFT)], 1);
    __syncthreads();

    int l0 = threadIdx.x, l1 = threadIdx.x + 256;
    int o0 = cnt[l0];
    int o1 = (W > 256) ? cnt[l1] : 0;
    for (int off = 1; off < W; off <<= 1) {
        int v0 = (l0 >= off) ? cnt[l0 - off] : 0;
        int v1 = 0;
        if (W > 256 && l1 >= off) v1 = cnt[l1 - off];
        __syncthreads();
        cnt[l0] += v0;
        if (W > 256) cnt[l1] += v1;
        __syncthreads();
    }
    int e0 = cnt[l0] - o0;
    int e1 = (W > 256) ? (cnt[l1] - o1) : 0;
    __syncthreads();
    cnt[l0] = base + e0;
    if (W > 256) cnt[l1] = base + e1;
    int g0 = (b << SHIFT) + l0;
    if (g0 < segn) ptr_excl[g0] = base + e0;
    if (W > 256) {
        int g1 = (b << SHIFT) + l1;
        if (g1 < segn) ptr_excl[g1] = base + e1;
    }
    if (b == NBK - 1 && threadIdx.x == 0) ptr_excl[segn] = NNZ;
    __syncthreads();

    bool fb = (bsize > SCAP);   // statistically never (bsize ~8163±90)
    for (int k = base + threadIdx.x; k < bend; k += 256) {
        int2 pr = pairs[k];
        int pos = atomicAdd(&cnt[pr.x - (b << SHIFT)], 1);
        if (!fb) stage[pos - base] = pr.y;
        else     csr[pos] = pr.y;
    }
    __syncthreads();
    if (!fb)
        for (int t = threadIdx.x; t < bsize; t += 256) csr[base + t] = stage[t];
}

// ---------------- GEMM: out[M,128] = act(H)[M,128] @ W[128,128] + gate*b ------
// OUT_BF16: out is the Hb gather table (eighth-major layout, stride NN rows).
template <bool PRELU_IN, bool PRELU_OUT, bool OUT_BF16>
__global__ __launch_bounds__(256) void gemm128(
        const float* __restrict__ H, const float* __restrict__ W,
        const float* __restrict__ bias, void* __restrict__ outv,
        float* __restrict__ out2 /*prelu'd fp32 copy, PRELU_OUT only*/,
        const int* __restrict__ gate /*per-row bias gate, may be null*/,
        int M, const float* __restrict__ a_ptr) {
    __shared__ float Wl[128 * 128];
    for (int i = threadIdx.x; i < 4096; i += 256)
        ((float4*)Wl)[i] = ((const float4*)W)[i];
    float a = 0.f;
    if (PRELU_IN || PRELU_OUT) a = *a_ptr;
    __syncthreads();

    const int jc = threadIdx.x & 15;
    const int rg = threadIdx.x >> 4;
    const int j0 = jc * 8;
    const int row0 = blockIdx.x * 64 + rg * 4;

    float acc[4][8];
#pragma unroll
    for (int r = 0; r < 4; ++r)
#pragma unroll
        for (int c = 0; c < 8; ++c) acc[r][c] = 0.f;

    int rclamp[4];
#pragma unroll
    for (int r = 0; r < 4; ++r) {
        int row = row0 + r;
        rclamp[r] = row < M ? row : (M - 1);
    }

#pragma unroll 2
    for (int k0 = 0; k0 < 128; k0 += 4) {
        float hr[4][4];
#pragma unroll
        for (int r = 0; r < 4; ++r) {
            float4 v = *(const float4*)(H + (size_t)rclamp[r] * DD + k0);
            if (PRELU_IN) {
                v.x = prelu(v.x, a); v.y = prelu(v.y, a);
                v.z = prelu(v.z, a); v.w = prelu(v.w, a);
            }
            hr[r][0] = v.x; hr[r][1] = v.y; hr[r][2] = v.z; hr[r][3] = v.w;
        }
#pragma unroll
        for (int kk = 0; kk < 4; ++kk) {
            const float4 w0 = *(const float4*)&Wl[(k0 + kk) * 128 + j0];
            const float4 w1 = *(const float4*)&Wl[(k0 + kk) * 128 + j0 + 4];
#pragma unroll
            for (int r = 0; r < 4; ++r) {
                float h = hr[r][kk];
                acc[r][0] += h * w0.x; acc[r][1] += h * w0.y;
                acc[r][2] += h * w0.z; acc[r][3] += h * w0.w;
                acc[r][4] += h * w1.x; acc[r][5] += h * w1.y;
                acc[r][6] += h * w1.z; acc[r][7] += h * w1.w;
            }
        }
    }

    float bb[8];
#pragma unroll
    for (int c = 0; c < 8; ++c) bb[c] = bias[j0 + c];

#pragma unroll
    for (int r = 0; r < 4; ++r) {
        int row = row0 + r;
        if (row < M) {
            float g = 1.f;
            if (gate) g = (gate[row] > 0) ? 1.f : 0.f;
            float o[8];
#pragma unroll
            for (int c = 0; c < 8; ++c) o[c] = acc[r][c] + bb[c] * g;
            if (OUT_BF16) {
                // Hb eighth-major: dims j0..j0+7 live in eighth j0>>4 at
                // within-offset j0&15 (0 or 8). 16B store, aligned.
                us8 o8;
                o8.lo = make_ushort4(f2bf(o[0]), f2bf(o[1]), f2bf(o[2]), f2bf(o[3]));
                o8.hi = make_ushort4(f2bf(o[4]), f2bf(o[5]), f2bf(o[6]), f2bf(o[7]));
                *(us8*)((unsigned short*)outv +
                        ((size_t)(j0 >> 4) * NN + row) * 16 + (j0 & 15)) = o8;
            } else {
                float* out = (float*)outv;
                *(float4*)(out + (size_t)row * DD + j0)     = make_float4(o[0], o[1], o[2], o[3]);
                *(float4*)(out + (size_t)row * DD + j0 + 4) = make_float4(o[4], o[5], o[6], o[7]);
            }
            if (PRELU_OUT) {
                *(float4*)(out2 + (size_t)row * DD + j0) =
                    make_float4(prelu(o[0], a), prelu(o[1], a), prelu(o[2], a), prelu(o[3], a));
                *(float4*)(out2 + (size_t)row * DD + j0 + 4) =
                    make_float4(prelu(o[4], a), prelu(o[5], a), prelu(o[6], a), prelu(o[7], a));
            }
        }
    }
}

// ---------------- edge features: Eb[j] = prelu(mean_{src in edge j} hv[src]) --
// XCD-affine eighth-slicing: block b handles dim-eighth e8 = b&7 only, so each
// XCD's random gathers stay inside a 3.2 MB Hb slice (L2-resident).
// Per CSR entry: 4 lanes x ushort4 (32B); 16 entries in flight per wave.
__global__ __launch_bounds__(256) void edge_agg(const unsigned short* __restrict__ Hb,
        const int* __restrict__ eptr, const int* __restrict__ ecsr,
        unsigned short* __restrict__ Eb, float* __restrict__ out_e,
        const float* __restrict__ a_ptr) {
    int b = blockIdx.x;
    int e8 = b & 7;                           // dim-eighth == XCD (round-robin)
    int j  = (b >> 3) * 4 + (threadIdx.x >> 6);
    int lane = threadIdx.x & 63;
    int g = lane >> 2, l4 = lane & 3;
    int p0 = eptr[j], p1 = eptr[j + 1];
    float a = *a_ptr;
    float s0 = 0.f, s1 = 0.f, s2 = 0.f, s3 = 0.f;
    const unsigned short* slice = Hb + (size_t)e8 * NN * 16;
    for (int p = p0 + g; p < p1; p += 16) {
        int row = ecsr[p];
        ushort4 v = *(const ushort4*)(slice + (size_t)row * 16 + l4 * 4);
        s0 += bf2f(v.x); s1 += bf2f(v.y); s2 += bf2f(v.z); s3 += bf2f(v.w);
    }
#pragma unroll
    for (int off = 4; off < 64; off <<= 1) {
        s0 += __shfl_xor(s0, off); s1 += __shfl_xor(s1, off);
        s2 += __shfl_xor(s2, off); s3 += __shfl_xor(s3, off);
    }
    if (g == 0) {
        float inv = 1.0f / fmaxf((float)(p1 - p0), 1.0f);
        float4 o = make_float4(prelu(s0 * inv, a), prelu(s1 * inv, a),
                               prelu(s2 * inv, a), prelu(s3 * inv, a));
        int q = e8 >> 1, hh = e8 & 1;
        *(ushort4*)(Eb + ((size_t)q * EE + j) * 32 + hh * 16 + l4 * 4) =
            make_ushort4(f2bf(o.x), f2bf(o.y), f2bf(o.z), f2bf(o.w));
        if (out_e)
            *(float4*)(out_e + (size_t)j * DD + e8 * 16 + l4 * 4) = o;
    }
}

// ---------------- node agg: nagg[i] = mean(Eb[dsts of i] ∪ prelu(hv[i])) ------
// XCD-affine quarter-slicing: block b handles dim-quarter q = (b&7)>>1; the two
// XCDs per quarter split the node space (h = b&1). Eb slice = 3.2 MB, resident.
// Per CSR entry: 4 lanes x 16B (us8); 16 entries in flight per wave.
__global__ __launch_bounds__(256) void node_agg(const unsigned short* __restrict__ Eb,
        const unsigned short* __restrict__ Hb, const int* __restrict__ nptr,
        const int* __restrict__ ncsr, float* __restrict__ Ag,
        const float* __restrict__ a_ptr) {
    int b = blockIdx.x;
    int xcd = b & 7;
    int q = xcd >> 1, h = xcd & 1;
    int i = (((b >> 3) * 2) + h) * 4 + (threadIdx.x >> 6);
    int lane = threadIdx.x & 63;
    int g = lane >> 2, l4 = lane & 3;
    int p0 = nptr[i], p1 = nptr[i + 1];
    float a = *a_ptr;
    float s0=0.f,s1=0.f,s2=0.f,s3=0.f,s4=0.f,s5=0.f,s6=0.f,s7=0.f;
    if (g == 0) {
        // self-loop term prelu(hv[i]) for dims q*32 + l4*8 .. +8
        // = Hb eighth 2q + (l4>>1), within-offset (l4&1)*8
        const us8 v = *(const us8*)(Hb +
            ((size_t)(2 * q + (l4 >> 1)) * NN + i) * 16 + (l4 & 1) * 8);
        s0 = prelu(bf2f(v.lo.x), a); s1 = prelu(bf2f(v.lo.y), a);
        s2 = prelu(bf2f(v.lo.z), a); s3 = prelu(bf2f(v.lo.w), a);
        s4 = prelu(bf2f(v.hi.x), a); s5 = prelu(bf2f(v.hi.y), a);
        s6 = prelu(bf2f(v.hi.z), a); s7 = prelu(bf2f(v.hi.w), a);
    }
    const unsigned short* slice = Eb + (size_t)q * EE * 32;
    for (int p = p0 + g; p < p1; p += 16) {
        int row = ncsr[p];
        const us8 v = *(const us8*)(slice + (size_t)row * 32 + l4 * 8);
        s0 += bf2f(v.lo.x); s1 += bf2f(v.lo.y);
        s2 += bf2f(v.lo.z); s3 += bf2f(v.lo.w);
        s4 += bf2f(v.hi.x); s5 += bf2f(v.hi.y);
        s6 += bf2f(v.hi.z); s7 += bf2f(v.hi.w);
    }
#pragma unroll
    for (int off = 4; off < 64; off <<= 1) {
        s0 += __shfl_xor(s0, off); s1 += __shfl_xor(s1, off);
        s2 += __shfl_xor(s2, off); s3 += __shfl_xor(s3, off);
        s4 += __shfl_xor(s4, off); s5 += __shfl_xor(s5, off);
        s6 += __shfl_xor(s6, off); s7 += __shfl_xor(s7, off);
    }
    if (g == 0) {
        float inv = 1.0f / (float)(p1 - p0 + 1);
        float* w = Ag + (size_t)i * DD + q * 32 + l4 * 8;
        *(float4*)(w)     = make_float4(s0 * inv, s1 * inv, s2 * inv, s3 * inv);
        *(float4*)(w + 4) = make_float4(s4 * inv, s5 * inv, s6 * inv, s7 * inv);
    }
}

// ---------------- component scatter: acc[comp[r]] += rows[r] (fp32 rows) ------
__global__ void comp_scatter(const float* __restrict__ rows, const int* __restrict__ comp,
                             float* __restrict__ acc, int M) {
    int i = blockIdx.x * blockDim.x + threadIdx.x;
    int stride = gridDim.x * blockDim.x;
    int total = M * DD;
    for (int k = i; k < total; k += stride) {
        int r = k >> 7, d = k & 127;
        atomicAdd(&acc[(size_t)comp[r] * DD + d], rows[k]);
    }
}

// ---------------- component scatter from quarter-major bf16 Eb -----------------
__global__ void comp_scatter_bf16(const unsigned short* __restrict__ Eb,
                                  const int* __restrict__ comp,
                                  float* __restrict__ acc, int M) {
    int i = blockIdx.x * blockDim.x + threadIdx.x;
    int stride = gridDim.x * blockDim.x;
    int total = M * DD;
    for (int k = i; k < total; k += stride) {
        int r = k >> 7, d = k & 127;
        unsigned short v = Eb[((size_t)(d >> 5) * EE + r) * 32 + (d & 31)];
        atomicAdd(&acc[(size_t)comp[r] * DD + d], bf2f(v));
    }
}

// ---------------- divide comp sums by counts to get means ----------------------
__global__ void cmean(float* __restrict__ c1, float* __restrict__ c2,
                      const int* __restrict__ cnt1, const int* __restrict__ cnt2) {
    int k = blockIdx.x * blockDim.x + threadIdx.x;
    if (k >= CC * DD) return;
    int r = k >> 7;
    c1[k] *= 1.0f / (float)max(cnt1[r], 1);
    c2[k] *= 1.0f / (float)max(cnt2[r], 1);
}

// ---------------- final c = prelu(c1row + c2row) -------------------------------
__global__ void c_final(const float* __restrict__ c1, const float* __restrict__ c2,
                        float* __restrict__ out, const float* __restrict__ a_ptr) {
    float a = *a_ptr;
    int k = blockIdx.x * blockDim.x + threadIdx.x;
    if (k >= CC * DD) return;
    out[k] = prelu(c1[k] + c2[k], a);
}

extern "C" void kernel_launch(void* const* d_in, const int* in_sizes, int n_in,
                              void* d_out, int out_size, void* d_ws, size_t ws_size,
                              hipStream_t stream) {
    const float* x     = (const float*)d_in[0];
    const int* he_idx  = (const int*)d_in[1];   // [2][NNZ]
    const int* hcomp   = (const int*)d_in[2];   // [2][EE]
    const int* ncomp   = (const int*)d_in[3];   // [2][NN]
    const float* a_ptr = (const float*)d_in[7];

    const float *W[8], *B[8];
    for (int l = 0; l < 2; ++l)
        for (int m = 0; m < 4; ++m) {
            W[l * 4 + m] = (const float*)d_in[8 + l * 8 + m * 2];
            B[l * 4 + m] = (const float*)d_in[8 + l * 8 + m * 2 + 1];
        }
    // W[0]=v2e_0 W[1]=e2v_0 W[2]=e2c_0 W[3]=n2c_0 ; W[4..7] = layer-1 same order

    const int* src = he_idx;            // row 0
    const int* dst = he_idx + NNZ;      // row 1
    const int* hec = hcomp + EE;        // edge -> component
    const int* ncc = ncomp + NN;        // node -> component

    // ---- workspace carve (~158 MiB) ----
    unsigned short* Hb = (unsigned short*)d_ws;      // [8][NN][16] bf16 (25.6MB)
    unsigned short* Eb = Hb + (size_t)NN * DD;       // [4][EE][32] bf16 (12.8MB)
    float* Ag = (float*)(Eb + (size_t)EE * DD);      // NN*128 fp32 nagg [pairs alias]
    float* Nb = Ag + (size_t)NN * DD;                // NN*128 fp32 n1/n2
    float* zreg = Nb + (size_t)NN * DD;              // ---- zero-init region ----
    float* c1acc = zreg;                             // CC*128
    float* c2acc = c1acc + CC * DD;                  // CC*128
    int* c1cnt   = (int*)(c2acc + CC * DD);          // CC
    int* c2cnt   = c1cnt + CC;                       // CC
    int* etot    = c2cnt + CC;                       // NBK
    int* ntot    = etot + NBK;                       // NBK
    size_t zbytes = (size_t)(2 * CC * DD + 2 * CC + 2 * NBK) * 4;
    // ---- non-zeroed scratch ----
    int* ebase   = ntot + NBK;                       // NBK+1
    int* nbase   = ebase + (NBK + 1);                // NBK+1
    int* ecur    = nbase + (NBK + 1);                // NBK
    int* ncur    = ecur + NBK;                       // NBK
    float* c1row = (float*)(ncur + NBK);             // CC*128
    float* c2row = c1row + CC * DD;                  // CC*128
    int* eptr    = (int*)(c2row + CC * DD);          // EE+1
    int* nptr    = eptr + (EE + 1);                  // NN+1
    int* csr_e   = nptr + (NN + 1);                  // NNZ
    int* csr_n   = csr_e + NNZ;                      // NNZ

    // pair arrays alias Ag (consumed by bucket_scatter before node_agg writes Ag)
    int2* pairs_e = (int2*)Ag;                       // NNZ int2 (12.8 MB)
    int2* pairs_n = pairs_e + NNZ;                   // NNZ int2 (12.8 MB)

    float* out_n = (float*)d_out;
    float* out_e = out_n + (size_t)NN * DD;
    float* out_c = out_e + (size_t)EE * DD;

    // ---- preprocessing: radix partition -> CSRs + ptrs ----
    hipMemsetAsync(zreg, 0, zbytes, stream);
    comp_hist<<<512, 256, 0, stream>>>(hec, ncc, c1cnt, c2cnt);
    part_hist<<<PB, 256, 0, stream>>>(src, dst, etot, ntot);
    scan_small<<<1, 256, 0, stream>>>(etot, ntot, ebase, nbase, ecur, ncur);
    reorder_kernel<<<PB, 256, 0, stream>>>(src, dst, ecur, ncur, pairs_e, pairs_n);
    bucket_scatter<256, 8><<<NBK, 256, 0, stream>>>(pairs_e, ebase, eptr, csr_e, EE);
    bucket_scatter<512, 9><<<NBK, 256, 0, stream>>>(pairs_n, nbase, nptr, csr_n, NN);

    const int gN  = (NN + 63) / 64;    // 1563
    const int gC  = (CC + 63) / 64;    // 32
    const int gEA = 8 * (EE / 4);      // 100000: eighth e8=b&7, 4 edges/block
    const int gNA = 8 * (NN / 8);      // 100000: quarter+half from b&7, 4 nodes/block

    // ---- layer 1 (only n feeds forward; e/c of layer 1 are dead) ----
    gemm128<false, false, true><<<gN, 256, 0, stream>>>(x, W[0], B[0], Hb, nullptr, nullptr, NN, a_ptr);   // hv1 -> Hb
    edge_agg<<<gEA, 256, 0, stream>>>(Hb, eptr, csr_e, Eb, nullptr, a_ptr);                                 // e1
    node_agg<<<gNA, 256, 0, stream>>>(Eb, Hb, nptr, csr_n, Ag, a_ptr);                                      // nagg1
    gemm128<false, false, false><<<gN, 256, 0, stream>>>(Ag, W[1], B[1], Nb, nullptr, nullptr, NN, a_ptr);  // n1 fp32

    // ---- layer 2 (input is prelu(n1), applied on load) ----
    gemm128<true, false, true><<<gN, 256, 0, stream>>>(Nb, W[4], B[4], Hb, nullptr, nullptr, NN, a_ptr);    // hv2 -> Hb
    edge_agg<<<gEA, 256, 0, stream>>>(Hb, eptr, csr_e, Eb, out_e, a_ptr);                                    // e2 + out_e
    node_agg<<<gNA, 256, 0, stream>>>(Eb, Hb, nptr, csr_n, Ag, a_ptr);                                       // nagg2
    gemm128<false, true, false><<<gN, 256, 0, stream>>>(Ag, W[5], B[5], Nb, out_n, nullptr, NN, a_ptr);     // n2, prelu->out_n

    // ---- component path (layer 2 only): aggregate FIRST, then tiny GEMMs ----
    comp_scatter_bf16<<<2048, 256, 0, stream>>>(Eb, hec, c1acc, EE);   // sum e2 rows by comp
    comp_scatter<<<2048, 256, 0, stream>>>(Nb, ncc, c2acc, NN);        // sum n2 rows by comp
    cmean<<<(CC * DD + 255) / 256, 256, 0, stream>>>(c1acc, c2acc, c1cnt, c2cnt);
    gemm128<false, false, false><<<gC, 256, 0, stream>>>(c1acc, W[6], B[6], c1row, nullptr, c1cnt, CC, a_ptr);
    gemm128<false, false, false><<<gC, 256, 0, stream>>>(c2acc, W[7], B[7], c2row, nullptr, c2cnt, CC, a_ptr);
    c_final<<<(CC * DD + 255) / 256, 256, 0, stream>>>(c1row, c2row, out_c, a_ptr);
}

// Round 7
// 897.018 us; speedup vs baseline: 1.2989x; 1.2989x over previous
//
#include <hip/hip_runtime.h>
#include <hip/hip_bf16.h>

// Problem constants (fixed by the reference's setup_inputs)
#define NN 100000      // nodes
#define EE 50000       // hyperedges
#define CC 2000        // components
#define NNZ 1600000    // incidences
#define DD 128         // feature dim
#define ET (EE + NN)   // edges incl. self-loop edges

// Radix-partition parameters
#define PB 800         // partition blocks
#define CHUNK 2000     // items per partition block (PB*CHUNK == NNZ exactly)
#define NBK 196        // coarse buckets (= ceil(EE/256) = ceil(NN/512))
#define SCAP 12288     // LDS staging capacity (entries) for bucket_scatter

__device__ __forceinline__ float prelu(float x, float a) {
    return x >= 0.f ? x : a * x;
}

// bf16 <-> f32 (RNE on store; exact on load)
__device__ __forceinline__ float bf2f(unsigned short h) {
    return __uint_as_float(((unsigned int)h) << 16);
}
__device__ __forceinline__ unsigned short f2bf(float f) {
    unsigned int u = __float_as_uint(f);
    u = (u + 0x7fff + ((u >> 16) & 1)) >> 16;
    return (unsigned short)u;
}

struct alignas(16) us8 { ushort4 lo, hi; };

// ---------------- pass A: coarse-bucket totals + component counts (merged) ----
__global__ __launch_bounds__(256) void part_hist(const int* __restrict__ src,
                                                 const int* __restrict__ dst,
                                                 int* __restrict__ etot,
                                                 int* __restrict__ ntot,
                                                 const int* __restrict__ hec,
                                                 const int* __restrict__ ncc,
                                                 int* __restrict__ c1cnt,
                                                 int* __restrict__ c2cnt) {
    __shared__ int he[NBK], hn[NBK];
    for (int i = threadIdx.x; i < NBK; i += 256) { he[i] = 0; hn[i] = 0; }
    __syncthreads();
    int b = blockIdx.x;
    int beg = b * CHUNK, end = min(beg + CHUNK, NNZ);
    for (int k = beg + threadIdx.x; k < end; k += 256) {
        atomicAdd(&he[dst[k] >> 8], 1);
        atomicAdd(&hn[src[k] >> 9], 1);
    }
    // merged comp_hist (grid-stride over EE and NN)
    int gid = b * 256 + threadIdx.x;
    int gstride = PB * 256;
    for (int k = gid; k < EE; k += gstride) atomicAdd(&c1cnt[hec[k]], 1);
    for (int k = gid; k < NN; k += gstride) atomicAdd(&c2cnt[ncc[k]], 1);
    __syncthreads();
    for (int i = threadIdx.x; i < NBK; i += 256) {
        if (he[i]) atomicAdd(&etot[i], he[i]);
        if (hn[i]) atomicAdd(&ntot[i], hn[i]);
    }
}

// ---------------- pass B: tiny scan of the 196-entry bucket totals ------------
__global__ __launch_bounds__(256) void scan_small(const int* __restrict__ etot,
        const int* __restrict__ ntot, int* __restrict__ ebase, int* __restrict__ nbase,
        int* __restrict__ ecur, int* __restrict__ ncur) {
    __shared__ int se[256], sn[256];
    int t = threadIdx.x;
    int ve = (t < NBK) ? etot[t] : 0;
    int vn = (t < NBK) ? ntot[t] : 0;
    se[t] = ve; sn[t] = vn;
    __syncthreads();
    for (int off = 1; off < 256; off <<= 1) {
        int ae = (t >= off) ? se[t - off] : 0;
        int an = (t >= off) ? sn[t - off] : 0;
        __syncthreads();
        se[t] += ae; sn[t] += an;
        __syncthreads();
    }
    if (t < NBK) {
        int be = se[t] - ve, bn = sn[t] - vn;
        ebase[t] = be; ecur[t] = be;
        nbase[t] = bn; ncur[t] = bn;
    }
    if (t == 0) { ebase[NBK] = NNZ; nbase[NBK] = NNZ; }
}

// ---------------- pass C: reorder pairs into bucket-contiguous order ----------
__global__ __launch_bounds__(256) void reorder_kernel(const int* __restrict__ src,
        const int* __restrict__ dst, int* __restrict__ ecur, int* __restrict__ ncur,
        int2* __restrict__ pe, int2* __restrict__ pn) {
    __shared__ int sS[CHUNK], sD[CHUNK];
    __shared__ int he[NBK], hn[NBK];
    __shared__ int beA[NBK], bnA[NBK];
    int b = blockIdx.x;
    int beg = b * CHUNK;
    int n = min(CHUNK, NNZ - beg);
    for (int i = threadIdx.x; i < NBK; i += 256) { he[i] = 0; hn[i] = 0; }
    for (int i = threadIdx.x; i < n; i += 256) {
        sS[i] = src[beg + i];
        sD[i] = dst[beg + i];
    }
    __syncthreads();
    for (int i = threadIdx.x; i < n; i += 256) {
        atomicAdd(&he[sD[i] >> 8], 1);
        atomicAdd(&hn[sS[i] >> 9], 1);
    }
    __syncthreads();
    for (int i = threadIdx.x; i < NBK; i += 256) {
        beA[i] = he[i] ? atomicAdd(&ecur[i], he[i]) : 0;
        bnA[i] = hn[i] ? atomicAdd(&ncur[i], hn[i]) : 0;
        he[i] = 0; hn[i] = 0;   // reuse as local cursors
    }
    __syncthreads();
    for (int i = threadIdx.x; i < n; i += 256) {
        int d = sD[i], s = sS[i];
        int bk = d >> 8;
        int p = beA[bk] + atomicAdd(&he[bk], 1);
        pe[p] = make_int2(d, s);            // key=dst, payload=src
        bk = s >> 9;
        p = bnA[bk] + atomicAdd(&hn[bk], 1);
        pn[p] = make_int2(s, d);            // key=src, payload=dst
    }
}

// ---------------- pass D: per-bucket exact CSR build --------------------------
template <int W, int SHIFT>
__global__ __launch_bounds__(256) void bucket_scatter(const int2* __restrict__ pairs,
        const int* __restrict__ bases, int* __restrict__ ptr_excl,
        int* __restrict__ csr, int segn) {
    __shared__ int cnt[W];
    __shared__ int stage[SCAP];
    int b = blockIdx.x;
    int base = bases[b];
    int bend = bases[b + 1];
    int bsize = bend - base;

    for (int i = threadIdx.x; i < W; i += 256) cnt[i] = 0;
    __syncthreads();
    for (int k = base + threadIdx.x; k < bend; k += 256)
        atomicAdd(&cnt[pairs[k].x - (b << SHIFT)], 1);
    __syncthreads();

    int l0 = threadIdx.x, l1 = threadIdx.x + 256;
    int o0 = cnt[l0];
    int o1 = (W > 256) ? cnt[l1] : 0;
    for (int off = 1; off < W; off <<= 1) {
        int v0 = (l0 >= off) ? cnt[l0 - off] : 0;
        int v1 = 0;
        if (W > 256 && l1 >= off) v1 = cnt[l1 - off];
        __syncthreads();
        cnt[l0] += v0;
        if (W > 256) cnt[l1] += v1;
        __syncthreads();
    }
    int e0 = cnt[l0] - o0;
    int e1 = (W > 256) ? (cnt[l1] - o1) : 0;
    __syncthreads();
    cnt[l0] = base + e0;
    if (W > 256) cnt[l1] = base + e1;
    int g0 = (b << SHIFT) + l0;
    if (g0 < segn) ptr_excl[g0] = base + e0;
    if (W > 256) {
        int g1 = (b << SHIFT) + l1;
        if (g1 < segn) ptr_excl[g1] = base + e1;
    }
    if (b == NBK - 1 && threadIdx.x == 0) ptr_excl[segn] = NNZ;
    __syncthreads();

    bool fb = (bsize > SCAP);   // statistically never (bsize ~8163±90)
    for (int k = base + threadIdx.x; k < bend; k += 256) {
        int2 pr = pairs[k];
        int pos = atomicAdd(&cnt[pr.x - (b << SHIFT)], 1);
        if (!fb) stage[pos - base] = pr.y;
        else     csr[pos] = pr.y;
    }
    __syncthreads();
    if (!fb)
        for (int t = threadIdx.x; t < bsize; t += 256) csr[base + t] = stage[t];
}

// ---------------- GEMM: out[M,128] = act(H)[M,128] @ W[128,128] + gate*b ------
// OUT_BF16: out is cast to ushort* (bf16 rows) -- used for the gather tables.
template <bool PRELU_IN, bool PRELU_OUT, bool OUT_BF16>
__global__ __launch_bounds__(256) void gemm128(
        const float* __restrict__ H, const float* __restrict__ W,
        const float* __restrict__ bias, void* __restrict__ outv,
        float* __restrict__ out2 /*prelu'd fp32 copy, PRELU_OUT only*/,
        const int* __restrict__ gate /*per-row bias gate, may be null*/,
        int M, const float* __restrict__ a_ptr) {
    __shared__ float Wl[128 * 128];
    for (int i = threadIdx.x; i < 4096; i += 256)
        ((float4*)Wl)[i] = ((const float4*)W)[i];
    float a = 0.f;
    if (PRELU_IN || PRELU_OUT) a = *a_ptr;
    __syncthreads();

    const int jc = threadIdx.x & 15;
    const int rg = threadIdx.x >> 4;
    const int j0 = jc * 8;
    const int row0 = blockIdx.x * 64 + rg * 4;

    float acc[4][8];
#pragma unroll
    for (int r = 0; r < 4; ++r)
#pragma unroll
        for (int c = 0; c < 8; ++c) acc[r][c] = 0.f;

    int rclamp[4];
#pragma unroll
    for (int r = 0; r < 4; ++r) {
        int row = row0 + r;
        rclamp[r] = row < M ? row : (M - 1);
    }

#pragma unroll 2
    for (int k0 = 0; k0 < 128; k0 += 4) {
        float hr[4][4];
#pragma unroll
        for (int r = 0; r < 4; ++r) {
            float4 v = *(const float4*)(H + (size_t)rclamp[r] * DD + k0);
            if (PRELU_IN) {
                v.x = prelu(v.x, a); v.y = prelu(v.y, a);
                v.z = prelu(v.z, a); v.w = prelu(v.w, a);
            }
            hr[r][0] = v.x; hr[r][1] = v.y; hr[r][2] = v.z; hr[r][3] = v.w;
        }
#pragma unroll
        for (int kk = 0; kk < 4; ++kk) {
            const float4 w0 = *(const float4*)&Wl[(k0 + kk) * 128 + j0];
            const float4 w1 = *(const float4*)&Wl[(k0 + kk) * 128 + j0 + 4];
#pragma unroll
            for (int r = 0; r < 4; ++r) {
                float h = hr[r][kk];
                acc[r][0] += h * w0.x; acc[r][1] += h * w0.y;
                acc[r][2] += h * w0.z; acc[r][3] += h * w0.w;
                acc[r][4] += h * w1.x; acc[r][5] += h * w1.y;
                acc[r][6] += h * w1.z; acc[r][7] += h * w1.w;
            }
        }
    }

    float bb[8];
#pragma unroll
    for (int c = 0; c < 8; ++c) bb[c] = bias[j0 + c];

#pragma unroll
    for (int r = 0; r < 4; ++r) {
        int row = row0 + r;
        if (row < M) {
            float g = 1.f;
            if (gate) g = (gate[row] > 0) ? 1.f : 0.f;
            float o[8];
#pragma unroll
            for (int c = 0; c < 8; ++c) o[c] = acc[r][c] + bb[c] * g;
            if (OUT_BF16) {
                us8 o8;
                o8.lo = make_ushort4(f2bf(o[0]), f2bf(o[1]), f2bf(o[2]), f2bf(o[3]));
                o8.hi = make_ushort4(f2bf(o[4]), f2bf(o[5]), f2bf(o[6]), f2bf(o[7]));
                *(us8*)((unsigned short*)outv + (size_t)row * DD + j0) = o8;
            } else {
                float* out = (float*)outv;
                *(float4*)(out + (size_t)row * DD + j0)     = make_float4(o[0], o[1], o[2], o[3]);
                *(float4*)(out + (size_t)row * DD + j0 + 4) = make_float4(o[4], o[5], o[6], o[7]);
            }
            if (PRELU_OUT) {
                *(float4*)(out2 + (size_t)row * DD + j0) =
                    make_float4(prelu(o[0], a), prelu(o[1], a), prelu(o[2], a), prelu(o[3], a));
                *(float4*)(out2 + (size_t)row * DD + j0 + 4) =
                    make_float4(prelu(o[4], a), prelu(o[5], a), prelu(o[6], a), prelu(o[7], a));
            }
        }
    }
}

// ---------------- edge features: Eb[j] = prelu(mean_{src in edge j} hv[src]) --
// One wave per edge; FOUR entries in flight (16-lane group per entry, us8 16B
// per lane = full 256B row per group) -> 2x the outstanding misses of r5.
__global__ __launch_bounds__(256) void edge_agg(const unsigned short* __restrict__ hv,
        const int* __restrict__ eptr, const int* __restrict__ ecsr,
        unsigned short* __restrict__ Eb, float* __restrict__ out_e,
        const float* __restrict__ a_ptr) {
    int j = blockIdx.x * 4 + (threadIdx.x >> 6);
    int lane = threadIdx.x & 63;
    int g = lane >> 4, l16 = lane & 15;
    int p0 = eptr[j], p1 = eptr[j + 1];
    float a = *a_ptr;
    float s0=0.f,s1=0.f,s2=0.f,s3=0.f,s4=0.f,s5=0.f,s6=0.f,s7=0.f;
    for (int p = p0 + g; p < p1; p += 4) {
        int row = ecsr[p];
        const us8 v = *(const us8*)(hv + (size_t)row * DD + l16 * 8);
        s0 += bf2f(v.lo.x); s1 += bf2f(v.lo.y);
        s2 += bf2f(v.lo.z); s3 += bf2f(v.lo.w);
        s4 += bf2f(v.hi.x); s5 += bf2f(v.hi.y);
        s6 += bf2f(v.hi.z); s7 += bf2f(v.hi.w);
    }
#pragma unroll
    for (int off = 16; off < 64; off <<= 1) {
        s0 += __shfl_xor(s0, off); s1 += __shfl_xor(s1, off);
        s2 += __shfl_xor(s2, off); s3 += __shfl_xor(s3, off);
        s4 += __shfl_xor(s4, off); s5 += __shfl_xor(s5, off);
        s6 += __shfl_xor(s6, off); s7 += __shfl_xor(s7, off);
    }
    if (g == 0) {
        float inv = 1.0f / fmaxf((float)(p1 - p0), 1.0f);
        float o[8] = { prelu(s0*inv,a), prelu(s1*inv,a), prelu(s2*inv,a), prelu(s3*inv,a),
                       prelu(s4*inv,a), prelu(s5*inv,a), prelu(s6*inv,a), prelu(s7*inv,a) };
        us8 ob;
        ob.lo = make_ushort4(f2bf(o[0]), f2bf(o[1]), f2bf(o[2]), f2bf(o[3]));
        ob.hi = make_ushort4(f2bf(o[4]), f2bf(o[5]), f2bf(o[6]), f2bf(o[7]));
        *(us8*)(Eb + (size_t)j * DD + l16 * 8) = ob;
        if (out_e) {
            float* w = out_e + (size_t)j * DD + l16 * 8;
            *(float4*)(w)     = make_float4(o[0], o[1], o[2], o[3]);
            *(float4*)(w + 4) = make_float4(o[4], o[5], o[6], o[7]);
        }
    }
}

// ---------------- node agg: nagg[i] = mean(Eb[dsts of i] ∪ prelu(hv[i])) ------
// Self-loop edge == prelu(hv[i]) computed inline (never materialized).
__global__ __launch_bounds__(256) void node_agg(const unsigned short* __restrict__ Eb,
        const unsigned short* __restrict__ hv, const int* __restrict__ nptr,
        const int* __restrict__ ncsr, float* __restrict__ nagg,
        const float* __restrict__ a_ptr) {
    int i = blockIdx.x * 4 + (threadIdx.x >> 6);
    int lane = threadIdx.x & 63;
    int g = lane >> 4, l16 = lane & 15;
    int p0 = nptr[i], p1 = nptr[i + 1];
    float a = *a_ptr;
    float s0=0.f,s1=0.f,s2=0.f,s3=0.f,s4=0.f,s5=0.f,s6=0.f,s7=0.f;
    if (g == 0) {   // self-loop contribution, exactly once
        const us8 v = *(const us8*)(hv + (size_t)i * DD + l16 * 8);
        s0 = prelu(bf2f(v.lo.x), a); s1 = prelu(bf2f(v.lo.y), a);
        s2 = prelu(bf2f(v.lo.z), a); s3 = prelu(bf2f(v.lo.w), a);
        s4 = prelu(bf2f(v.hi.x), a); s5 = prelu(bf2f(v.hi.y), a);
        s6 = prelu(bf2f(v.hi.z), a); s7 = prelu(bf2f(v.hi.w), a);
    }
    for (int p = p0 + g; p < p1; p += 4) {
        int row = ncsr[p];
        const us8 v = *(const us8*)(Eb + (size_t)row * DD + l16 * 8);
        s0 += bf2f(v.lo.x); s1 += bf2f(v.lo.y);
        s2 += bf2f(v.lo.z); s3 += bf2f(v.lo.w);
        s4 += bf2f(v.hi.x); s5 += bf2f(v.hi.y);
        s6 += bf2f(v.hi.z); s7 += bf2f(v.hi.w);
    }
#pragma unroll
    for (int off = 16; off < 64; off <<= 1) {
        s0 += __shfl_xor(s0, off); s1 += __shfl_xor(s1, off);
        s2 += __shfl_xor(s2, off); s3 += __shfl_xor(s3, off);
        s4 += __shfl_xor(s4, off); s5 += __shfl_xor(s5, off);
        s6 += __shfl_xor(s6, off); s7 += __shfl_xor(s7, off);
    }
    if (g == 0) {
        float inv = 1.0f / (float)(p1 - p0 + 1);
        float* w = nagg + (size_t)i * DD + l16 * 8;
        *(float4*)(w)     = make_float4(s0 * inv, s1 * inv, s2 * inv, s3 * inv);
        *(float4*)(w + 4) = make_float4(s4 * inv, s5 * inv, s6 * inv, s7 * inv);
    }
}

// ---------------- component scatter: acc[comp[r]] += rows[r] (fp32 rows) ------
__global__ void comp_scatter(const float* __restrict__ rows, const int* __restrict__ comp,
                             float* __restrict__ acc, int M) {
    int i = blockIdx.x * blockDim.x + threadIdx.x;
    int stride = gridDim.x * blockDim.x;
    int total = M * DD;
    for (int k = i; k < total; k += stride) {
        int r = k >> 7, d = k & 127;
        atomicAdd(&acc[(size_t)comp[r] * DD + d], rows[k]);
    }
}

// ---------------- component scatter from bf16 rows -----------------------------
__global__ void comp_scatter_bf16(const unsigned short* __restrict__ rows,
                                  const int* __restrict__ comp,
                                  float* __restrict__ acc, int M) {
    int i = blockIdx.x * blockDim.x + threadIdx.x;
    int stride = gridDim.x * blockDim.x;
    int total = M * DD;
    for (int k = i; k < total; k += stride) {
        int r = k >> 7, d = k & 127;
        atomicAdd(&acc[(size_t)comp[r] * DD + d], bf2f(rows[k]));
    }
}

// ---------------- divide comp sums by counts to get means ----------------------
__global__ void cmean(float* __restrict__ c1, float* __restrict__ c2,
                      const int* __restrict__ cnt1, const int* __restrict__ cnt2) {
    int k = blockIdx.x * blockDim.x + threadIdx.x;
    if (k >= CC * DD) return;
    int r = k >> 7;
    c1[k] *= 1.0f / (float)max(cnt1[r], 1);
    c2[k] *= 1.0f / (float)max(cnt2[r], 1);
}

// ---------------- final c = prelu(c1row + c2row) -------------------------------
__global__ void c_final(const float* __restrict__ c1, const float* __restrict__ c2,
                        float* __restrict__ out, const float* __restrict__ a_ptr) {
    float a = *a_ptr;
    int k = blockIdx.x * blockDim.x + threadIdx.x;
    if (k >= CC * DD) return;
    out[k] = prelu(c1[k] + c2[k], a);
}

extern "C" void kernel_launch(void* const* d_in, const int* in_sizes, int n_in,
                              void* d_out, int out_size, void* d_ws, size_t ws_size,
                              hipStream_t stream) {
    const float* x     = (const float*)d_in[0];
    const int* he_idx  = (const int*)d_in[1];   // [2][NNZ]
    const int* hcomp   = (const int*)d_in[2];   // [2][EE]
    const int* ncomp   = (const int*)d_in[3];   // [2][NN]
    const float* a_ptr = (const float*)d_in[7];

    const float *W[8], *B[8];
    for (int l = 0; l < 2; ++l)
        for (int m = 0; m < 4; ++m) {
            W[l * 4 + m] = (const float*)d_in[8 + l * 8 + m * 2];
            B[l * 4 + m] = (const float*)d_in[8 + l * 8 + m * 2 + 1];
        }
    // W[0]=v2e_0 W[1]=e2v_0 W[2]=e2c_0 W[3]=n2c_0 ; W[4..7] = layer-1 same order

    const int* src = he_idx;            // row 0
    const int* dst = he_idx + NNZ;      // row 1
    const int* hec = hcomp + EE;        // edge -> component
    const int* ncc = ncomp + NN;        // node -> component

    // ---- workspace carve (~158 MiB) ----
    unsigned short* Hb = (unsigned short*)d_ws;      // NN*128 bf16 hv table (25.6MB)
    unsigned short* Eb = Hb + (size_t)NN * DD;       // EE*128 bf16 E table (12.8MB)
    float* Ag = (float*)(Eb + (size_t)EE * DD);      // NN*128 fp32 nagg [pairs alias]
    float* Nb = Ag + (size_t)NN * DD;                // NN*128 fp32 n1/n2
    float* zreg = Nb + (size_t)NN * DD;              // ---- zero-init region ----
    float* c1acc = zreg;                             // CC*128
    float* c2acc = c1acc + CC * DD;                  // CC*128
    int* c1cnt   = (int*)(c2acc + CC * DD);          // CC
    int* c2cnt   = c1cnt + CC;                       // CC
    int* etot    = c2cnt + CC;                       // NBK
    int* ntot    = etot + NBK;                       // NBK
    size_t zbytes = (size_t)(2 * CC * DD + 2 * CC + 2 * NBK) * 4;
    // ---- non-zeroed scratch ----
    int* ebase   = ntot + NBK;                       // NBK+1
    int* nbase   = ebase + (NBK + 1);                // NBK+1
    int* ecur    = nbase + (NBK + 1);                // NBK
    int* ncur    = ecur + NBK;                       // NBK
    float* c1row = (float*)(ncur + NBK);             // CC*128
    float* c2row = c1row + CC * DD;                  // CC*128
    int* eptr    = (int*)(c2row + CC * DD);          // EE+1
    int* nptr    = eptr + (EE + 1);                  // NN+1
    int* csr_e   = nptr + (NN + 1);                  // NNZ
    int* csr_n   = csr_e + NNZ;                      // NNZ

    // pair arrays alias Ag (consumed by bucket_scatter before node_agg writes Ag)
    int2* pairs_e = (int2*)Ag;                       // NNZ int2 (12.8 MB)
    int2* pairs_n = pairs_e + NNZ;                   // NNZ int2 (12.8 MB)

    float* out_n = (float*)d_out;
    float* out_e = out_n + (size_t)NN * DD;
    float* out_c = out_e + (size_t)EE * DD;

    // ---- preprocessing: radix partition -> CSRs + ptrs ----
    hipMemsetAsync(zreg, 0, zbytes, stream);
    part_hist<<<PB, 256, 0, stream>>>(src, dst, etot, ntot, hec, ncc, c1cnt, c2cnt);
    scan_small<<<1, 256, 0, stream>>>(etot, ntot, ebase, nbase, ecur, ncur);
    reorder_kernel<<<PB, 256, 0, stream>>>(src, dst, ecur, ncur, pairs_e, pairs_n);
    bucket_scatter<256, 8><<<NBK, 256, 0, stream>>>(pairs_e, ebase, eptr, csr_e, EE);
    bucket_scatter<512, 9><<<NBK, 256, 0, stream>>>(pairs_n, nbase, nptr, csr_n, NN);

    const int gN  = (NN + 63) / 64;    // 1563
    const int gC  = (CC + 63) / 64;    // 32
    const int gEA = EE / 4;            // 12500
    const int gNA = NN / 4;            // 25000

    // ---- layer 1 (only n feeds forward; e/c of layer 1 are dead) ----
    gemm128<false, false, true><<<gN, 256, 0, stream>>>(x, W[0], B[0], Hb, nullptr, nullptr, NN, a_ptr);   // hv1 -> bf16
    edge_agg<<<gEA, 256, 0, stream>>>(Hb, eptr, csr_e, Eb, nullptr, a_ptr);                                 // e1
    node_agg<<<gNA, 256, 0, stream>>>(Eb, Hb, nptr, csr_n, Ag, a_ptr);                                      // nagg1
    gemm128<false, false, false><<<gN, 256, 0, stream>>>(Ag, W[1], B[1], Nb, nullptr, nullptr, NN, a_ptr);  // n1 fp32

    // ---- layer 2 (input is prelu(n1), applied on load) ----
    gemm128<true, false, true><<<gN, 256, 0, stream>>>(Nb, W[4], B[4], Hb, nullptr, nullptr, NN, a_ptr);    // hv2 -> bf16
    edge_agg<<<gEA, 256, 0, stream>>>(Hb, eptr, csr_e, Eb, out_e, a_ptr);                                    // e2 + out_e
    node_agg<<<gNA, 256, 0, stream>>>(Eb, Hb, nptr, csr_n, Ag, a_ptr);                                       // nagg2
    gemm128<false, true, false><<<gN, 256, 0, stream>>>(Ag, W[5], B[5], Nb, out_n, nullptr, NN, a_ptr);     // n2, prelu->out_n

    // ---- component path (layer 2 only): aggregate FIRST, then tiny GEMMs ----
    comp_scatter_bf16<<<2048, 256, 0, stream>>>(Eb, hec, c1acc, EE);   // sum e2 rows by comp
    comp_scatter<<<2048, 256, 0, stream>>>(Nb, ncc, c2acc, NN);        // sum n2 rows by comp
    cmean<<<(CC * DD + 255) / 256, 256, 0, stream>>>(c1acc, c2acc, c1cnt, c2cnt);
    gemm128<false, false, false><<<gC, 256, 0, stream>>>(c1acc, W[6], B[6], c1row, nullptr, c1cnt, CC, a_ptr);
    gemm128<false, false, false><<<gC, 256, 0, stream>>>(c2acc, W[7], B[7], c2row, nullptr, c2cnt, CC, a_ptr);
    c_final<<<(CC * DD + 255) / 256, 256, 0, stream>>>(c1row, c2row, out_c, a_ptr);
}